// Round 12
// baseline (61.607 us; speedup 1.0000x reference)
//
#include <hip/hip_runtime.h>
#include <math.h>
#include <float.h>

#define Hd 512
#define Wd 512
#define HWp (Hd*Wd)
#define Bn 16
#define Cn 3
#define NMAP (Bn*Cn)
#define KTOP 500
#define PBANDS 16           // bands per map (K1 blocks per map)
#define BAND 32             // rows per band
#define CAPB 4096           // exact worst-case peaks in 32x512 band (16*256)

__device__ __forceinline__ uint32_t flipbits(float v){
  uint32_t u = __float_as_uint(v);
  return u ^ (0x80000000u | (uint32_t)(-(int32_t)(u>>31)));
}
__device__ __forceinline__ float unflipbits(uint32_t f){
  uint32_t u = f ^ ((f>>31)? 0x80000000u : 0xFFFFFFFFu);
  return __uint_as_float(u);
}

// ---- 3x3 NMS for one row of 8 px/lane, all operands in registers ----
__device__ __forceinline__ void nms_row(
    const float4 p0, const float4 p1, const float4 c0, const float4 c1,
    const float4 n0, const float4 n1, const int lane,
    uint32_t& pk, float* cv)
{
  float vm0 = fmaxf(fmaxf(p0.x,c0.x),n0.x);
  float vm1 = fmaxf(fmaxf(p0.y,c0.y),n0.y);
  float vm2 = fmaxf(fmaxf(p0.z,c0.z),n0.z);
  float vm3 = fmaxf(fmaxf(p0.w,c0.w),n0.w);
  float vm4 = fmaxf(fmaxf(p1.x,c1.x),n1.x);
  float vm5 = fmaxf(fmaxf(p1.y,c1.y),n1.y);
  float vm6 = fmaxf(fmaxf(p1.z,c1.z),n1.z);
  float vm7 = fmaxf(fmaxf(p1.w,c1.w),n1.w);
  float vmL = __shfl_up(vm7, 1);   if (lane == 0)  vmL = -INFINITY;
  float vmR = __shfl_down(vm0, 1); if (lane == 63) vmR = -INFINITY;

  float m0 = fmaxf(vmL, fmaxf(vm0, vm1));
  float m1 = fmaxf(vm0, fmaxf(vm1, vm2));
  float m2 = fmaxf(vm1, fmaxf(vm2, vm3));
  float m3 = fmaxf(vm2, fmaxf(vm3, vm4));
  float m4 = fmaxf(vm3, fmaxf(vm4, vm5));
  float m5 = fmaxf(vm4, fmaxf(vm5, vm6));
  float m6 = fmaxf(vm5, fmaxf(vm6, vm7));
  float m7 = fmaxf(vm6, fmaxf(vm7, vmR));

  pk = 0;
  if (c0.x >= m0) pk |= 1u;
  if (c0.y >= m1) pk |= 2u;
  if (c0.z >= m2) pk |= 4u;
  if (c0.w >= m3) pk |= 8u;
  if (c1.x >= m4) pk |= 16u;
  if (c1.y >= m5) pk |= 32u;
  if (c1.z >= m6) pk |= 64u;
  if (c1.w >= m7) pk |= 128u;
  cv[0]=c0.x; cv[1]=c0.y; cv[2]=c0.z; cv[3]=c0.w;
  cv[4]=c1.x; cv[5]=c1.y; cv[6]=c1.z; cv[7]=c1.w;
}

// ============ Kernel 1: pure NMS -> per-block global segment (no LDS staging) ============
__global__ __launch_bounds__(512) void k_nms(
    const float* __restrict__ hm, uint64_t* __restrict__ seg_all,
    uint32_t* __restrict__ cnt)
{
  __shared__ uint32_t ctr;
  const int bid = blockIdx.x;
  const int m = bid >> 4, p = bid & (PBANDS - 1);
  const int tid = threadIdx.x, lane = tid & 63, w = tid >> 6;
  const float* map = hm + (size_t)m * HWp;
  uint64_t* dst = seg_all + (size_t)bid * CAPB;
  const int y0 = p * BAND + w * 4;
  const int xb = lane * 8;

  if (tid == 0) ctr = 0;
  __syncthreads();

  // upfront load of the 6 rows this wave needs (12 independent float4 loads)
  const float4 NEG4 = make_float4(-INFINITY,-INFINITY,-INFINITY,-INFINITY);
  float4 ra[6], rb[6];
  #pragma unroll
  for (int r = 0; r < 6; ++r) {
    const int yy = y0 - 1 + r;
    if (yy >= 0 && yy < Hd) {
      const float* rp = map + (size_t)yy * Wd + xb;
      ra[r] = *(const float4*)rp; rb[r] = *(const float4*)(rp + 4);
    } else { ra[r] = NEG4; rb[r] = NEG4; }
  }

  #pragma unroll
  for (int r = 0; r < 4; ++r) {
    uint32_t pk; float cv[8];
    nms_row(ra[r], rb[r], ra[r+1], rb[r+1], ra[r+2], rb[r+2], lane, pk, cv);
    // one wave-scan, then static serial store loop to consecutive global slots
    const uint32_t np = (uint32_t)__popc(pk);
    uint32_t incl = np;
    #pragma unroll
    for (int d = 1; d < 64; d <<= 1) { uint32_t u = __shfl_up(incl, d); if (lane >= d) incl += u; }
    const uint32_t tot = __shfl(incl, 63);
    if (!tot) continue;
    uint32_t b0 = 0;
    if (lane == 0) b0 = atomicAdd(&ctr, tot);
    b0 = __shfl(b0, 0);
    uint32_t pos = b0 + incl - np;
    const uint32_t ib = (uint32_t)((y0 + r) * Wd + xb);
    #pragma unroll
    for (int i = 0; i < 8; ++i) {
      if ((pk >> i) & 1u) {
        if (pos < (uint32_t)CAPB)
          dst[pos] = ((uint64_t)flipbits(cv[i]) << 32) | (uint32_t)(~(ib + (uint32_t)i));
        ++pos;
      }
    }
  }
  __syncthreads();
  if (tid == 0) cnt[bid] = (ctr < (uint32_t)CAPB) ? ctr : (uint32_t)CAPB;
}

// ---- threshold finder: 4096 bins, 1024 threads (4 bins/thread), 2 barriers ----
// res: [0]=bin, [1]=krem, [2]=M (count of keys in bins >= bin)
__device__ __forceinline__ void findT4096(
    const uint32_t* hist, const uint32_t target, const int tid, const int lane,
    const int wid, uint32_t* wtot, uint32_t* res)
{
  const uint32_t s = hist[4*tid] + hist[4*tid+1] + hist[4*tid+2] + hist[4*tid+3];
  uint32_t v = s;
  #pragma unroll
  for (int d = 1; d < 64; d <<= 1) { uint32_t u = __shfl_down(v, d); if (lane + d < 64) v += u; }
  if (lane == 0) wtot[wid] = v;
  __syncthreads();
  uint32_t above = 0;
  for (int ww = wid + 1; ww < 16; ++ww) above += wtot[ww];
  const uint32_t gsuf = v + above;
  if (gsuf >= target && (gsuf - s) < target) {
    uint32_t cum = gsuf - s;
    for (int b = 4*tid + 3; b >= 4*tid; --b) {
      cum += hist[b];
      if (cum >= target) { res[0]=(uint32_t)b; res[1]=target-(cum-hist[b]); res[2]=cum; break; }
    }
  }
  __syncthreads();
}

// ============ Kernel 2: per-map top-500 via hist-threshold + rank-by-count ============
__global__ __launch_bounds__(1024) void k_select(
    const uint64_t* __restrict__ seg_all, const uint32_t* __restrict__ cnt,
    float* __restrict__ s1_scores, uint32_t* __restrict__ s1_inds)
{
  __shared__ uint32_t hist[4096];   // 16 KB
  __shared__ uint64_t csel[1024];   // 8 KB
  __shared__ uint32_t wtot[16];
  __shared__ uint32_t res[4];       // 0:bin 1:krem 2:M0 3:append ctr

  const int m = blockIdx.x;
  const int tid = threadIdx.x, lane = tid & 63, wid = tid >> 6;
  const uint64_t lt = (1ull << lane) - 1ull;

  for (int i = tid; i < 4096; i += 1024) hist[i] = 0;
  if (tid == 0) res[3] = 0;
  __syncthreads();

  // wave <-> segment mapping (16 waves, 16 bands per map)
  const uint64_t* sg = seg_all + (size_t)(m * PBANDS + wid) * CAPB;
  const uint32_t sn = min(cnt[m * PBANDS + wid], (uint32_t)CAPB);

  // ---- scan 1: 12-bit histogram, 4 loads in flight per lane ----
  for (uint32_t base = 0; base < sn; base += 256u) {
    const uint32_t i0 = base + (uint32_t)lane, i1 = i0 + 64u, i2 = i0 + 128u, i3 = i0 + 192u;
    uint64_t k0 = 0, k1 = 0, k2 = 0, k3 = 0;
    if (i0 < sn) k0 = sg[i0];
    if (i1 < sn) k1 = sg[i1];
    if (i2 < sn) k2 = sg[i2];
    if (i3 < sn) k3 = sg[i3];
    if (i0 < sn) atomicAdd(&hist[(uint32_t)(k0 >> 52)], 1u);
    if (i1 < sn) atomicAdd(&hist[(uint32_t)(k1 >> 52)], 1u);
    if (i2 < sn) atomicAdd(&hist[(uint32_t)(k2 >> 52)], 1u);
    if (i3 < sn) atomicAdd(&hist[(uint32_t)(k3 >> 52)], 1u);
  }
  __syncthreads();

  findT4096(hist, KTOP, tid, lane, wid, wtot, res);
  const uint32_t T1 = res[0], krem = res[1], M0 = res[2];
  __syncthreads();

  uint32_t shift = 20, thr = T1;
  if (M0 > 1024u) {
    // rare: refine 12 more bits over keys in bin T1
    for (int i = tid; i < 4096; i += 1024) hist[i] = 0;
    __syncthreads();
    for (uint32_t i = (uint32_t)lane; i < sn; i += 64u) {
      const uint32_t f = (uint32_t)(sg[i] >> 32);
      if ((f >> 20) == T1) atomicAdd(&hist[(f >> 8) & 4095u], 1u);
    }
    __syncthreads();
    findT4096(hist, krem, tid, lane, wid, wtot, res);
    shift = 8; thr = (T1 << 12) | res[0];
    __syncthreads();
  }

  // ---- scan 2: compact survivors into csel (wave-aggregated LDS append) ----
  for (uint32_t base = 0; base < sn; base += 256u) {
    const uint32_t i0 = base + (uint32_t)lane, i1 = i0 + 64u, i2 = i0 + 128u, i3 = i0 + 192u;
    uint64_t k0 = 0, k1 = 0, k2 = 0, k3 = 0;
    if (i0 < sn) k0 = sg[i0];
    if (i1 < sn) k1 = sg[i1];
    if (i2 < sn) k2 = sg[i2];
    if (i3 < sn) k3 = sg[i3];
    const bool p0 = (i0 < sn) && (((uint32_t)(k0 >> 32) >> shift) >= thr);
    const bool p1 = (i1 < sn) && (((uint32_t)(k1 >> 32) >> shift) >= thr);
    const bool p2 = (i2 < sn) && (((uint32_t)(k2 >> 32) >> shift) >= thr);
    const bool p3 = (i3 < sn) && (((uint32_t)(k3 >> 32) >> shift) >= thr);
    #define APP(K, P) {                                                  \
      const unsigned long long mask = __ballot(P);                       \
      if (mask) {                                                        \
        uint32_t b = 0;                                                  \
        if (lane == 0) b = atomicAdd(&res[3], (uint32_t)__popcll(mask)); \
        b = __shfl(b, 0);                                                \
        if (P) {                                                         \
          const uint32_t pp = b + (uint32_t)__popcll(mask & lt);         \
          if (pp < 1024u) csel[pp] = K;                                  \
        }                                                                \
      }                                                                  \
    }
    APP(k0, p0) APP(k1, p1) APP(k2, p2) APP(k3, p3)
    #undef APP
  }
  __syncthreads();
  uint32_t M = res[3]; if (M > 1024u) M = 1024u;
  const uint32_t Mp = (M + 3u) & ~3u;
  if ((uint32_t)tid >= M && (uint32_t)tid < Mp) csel[tid] = 0ull;   // pad for 4-wide loop
  __syncthreads();

  // ---- exact rank by count (keys unique; ties impossible) ----
  const uint64_t kk = ((uint32_t)tid < M) ? csel[tid] : 0ull;
  uint32_t rank = 0;
  for (uint32_t j = 0; j < Mp; j += 4u) {
    rank += (csel[j]   > kk) ? 1u : 0u;
    rank += (csel[j+1] > kk) ? 1u : 0u;
    rank += (csel[j+2] > kk) ? 1u : 0u;
    rank += (csel[j+3] > kk) ? 1u : 0u;
  }
  if ((uint32_t)tid < M && rank < 512u) {
    const float v = unflipbits((uint32_t)(kk >> 32));
    s1_scores[m * 512 + rank] = 1.0f / (1.0f + expf(-v));
    s1_inds [m * 512 + rank] = ~(uint32_t)kk;
  }
  if ((uint32_t)tid >= M && tid < 512) {   // safety fill if M < 512
    s1_scores[m * 512 + tid] = 0.0f;
    s1_inds [m * 512 + tid] = 0u;
  }
}

// ============ Kernel 3: per-(batch,class) rank + gather + emit (48 blocks) ============
__global__ __launch_bounds__(512) void k_final(
    const float* __restrict__ s1_scores, const uint32_t* __restrict__ s1_inds,
    const float* __restrict__ cen_offset, const float* __restrict__ direction,
    const float* __restrict__ z_coor, const float* __restrict__ dimf,
    float* __restrict__ out)
{
  __shared__ float ssc[Cn][KTOP];
  const int b = blockIdx.x / Cn, c = blockIdx.x % Cn;
  const int tid = threadIdx.x;

  for (int i = tid; i < Cn * KTOP; i += 512) {
    int cc = i / KTOP, r = i - cc * KTOP;
    ssc[cc][r] = s1_scores[(b * Cn + cc) * 512 + r];
  }
  __syncthreads();

  if (tid < KTOP) {
    const int r = tid;
    const int i = c * KTOP + r;
    const uint64_t mykey = ((uint64_t)flipbits(ssc[c][r]) << 32) | (uint32_t)(~(uint32_t)i);
    int rank = r;
    #pragma unroll
    for (int cd = 1; cd < Cn; ++cd) {
      const int cc = (c + cd) % Cn;
      int lo = 0, hi = KTOP;
      while (lo < hi) {
        int mid = (lo + hi) >> 1;
        uint64_t k2 = ((uint64_t)flipbits(ssc[cc][mid]) << 32)
                    | (uint32_t)(~(uint32_t)(cc * KTOP + mid));
        if (k2 > mykey) lo = mid + 1; else hi = mid;
      }
      rank += lo;
    }
    if (rank < KTOP) {
      const float* co = cen_offset + (size_t)b * 2 * HWp;
      const float* di = direction  + (size_t)b * 2 * HWp;
      const float* zc = z_coor     + (size_t)b * HWp;
      const float* dm = dimf       + (size_t)b * 3 * HWp;
      const int bcx = b * Cn + c;
      const uint32_t ind = s1_inds[bcx * 512 + r];
      float o[10];
      o[0] = ssc[c][r];
      o[1] = (float)(ind & (Wd - 1)) + co[ind];
      o[2] = (float)(ind >> 9) + co[HWp + ind];
      o[3] = zc[ind];
      o[4] = dm[ind];
      o[5] = dm[HWp + ind];
      o[6] = dm[2 * HWp + ind];
      o[7] = di[ind];
      o[8] = di[HWp + ind];
      o[9] = (float)c;
      float* op = out + ((size_t)b * KTOP + rank) * 10;
      #pragma unroll
      for (int q = 0; q < 10; ++q) op[q] = o[q];
    }
  }
}

extern "C" void kernel_launch(void* const* d_in, const int* in_sizes, int n_in,
                              void* d_out, int out_size, void* d_ws, size_t ws_size,
                              hipStream_t stream)
{
  const float* hm         = (const float*)d_in[0];
  const float* cen_offset = (const float*)d_in[1];
  const float* direction  = (const float*)d_in[2];
  const float* z_coor     = (const float*)d_in[3];
  const float* dimf       = (const float*)d_in[4];
  float* out = (float*)d_out;

  // ws: cnt[768]u32 (pad 4KB) | s1_sc[48*512]f32 | s1_id[48*512]u32 | seg[768*4096]u64 (25.2MB)
  char* ws = (char*)d_ws;
  uint32_t* cnt   = (uint32_t*)ws;
  float*    s1_sc = (float*)(ws + 4096);
  uint32_t* s1_id = (uint32_t*)(ws + 4096 + (size_t)NMAP * 512 * 4);
  size_t fixed    = 4096 + (size_t)NMAP * 512 * 4 * 2;
  uint64_t* seg   = (uint64_t*)(ws + fixed);

  k_nms   <<<NMAP * PBANDS, 512, 0, stream>>>(hm, seg, cnt);
  k_select<<<NMAP,         1024, 0, stream>>>(seg, cnt, s1_sc, s1_id);
  k_final <<<Bn * Cn,       512, 0, stream>>>(s1_sc, s1_id, cen_offset, direction, z_coor, dimf, out);
}

// Round 13
// 54.137 us; speedup vs baseline: 1.1380x; 1.1380x over previous
//
#include <hip/hip_runtime.h>
#include <math.h>
#include <float.h>

#define Hd 512
#define Wd 512
#define HWp (Hd*Wd)
#define Bn 16
#define Cn 3
#define NMAP (Bn*Cn)
#define KTOP 500
#define PBANDS 16           // bands per map (K1 blocks per map)
#define BAND 32             // rows per band
#define CAPB 4096           // worst-case peaks (no-ties) in a 32x512 band

__device__ __forceinline__ uint32_t flipbits(float v){
  uint32_t u = __float_as_uint(v);
  return u ^ (0x80000000u | (uint32_t)(-(int32_t)(u>>31)));
}
__device__ __forceinline__ float unflipbits(uint32_t f){
  uint32_t u = f ^ ((f>>31)? 0x80000000u : 0xFFFFFFFFu);
  return __uint_as_float(u);
}

// ---- 3x3 NMS for one row of 8 px/lane, all operands in registers ----
__device__ __forceinline__ void nms_row(
    const float4 p0, const float4 p1, const float4 c0, const float4 c1,
    const float4 n0, const float4 n1, const int lane,
    uint32_t& pk, float* cv)
{
  float vm0 = fmaxf(fmaxf(p0.x,c0.x),n0.x);
  float vm1 = fmaxf(fmaxf(p0.y,c0.y),n0.y);
  float vm2 = fmaxf(fmaxf(p0.z,c0.z),n0.z);
  float vm3 = fmaxf(fmaxf(p0.w,c0.w),n0.w);
  float vm4 = fmaxf(fmaxf(p1.x,c1.x),n1.x);
  float vm5 = fmaxf(fmaxf(p1.y,c1.y),n1.y);
  float vm6 = fmaxf(fmaxf(p1.z,c1.z),n1.z);
  float vm7 = fmaxf(fmaxf(p1.w,c1.w),n1.w);
  float vmL = __shfl_up(vm7, 1);   if (lane == 0)  vmL = -INFINITY;
  float vmR = __shfl_down(vm0, 1); if (lane == 63) vmR = -INFINITY;

  float m0 = fmaxf(vmL, fmaxf(vm0, vm1));
  float m1 = fmaxf(vm0, fmaxf(vm1, vm2));
  float m2 = fmaxf(vm1, fmaxf(vm2, vm3));
  float m3 = fmaxf(vm2, fmaxf(vm3, vm4));
  float m4 = fmaxf(vm3, fmaxf(vm4, vm5));
  float m5 = fmaxf(vm4, fmaxf(vm5, vm6));
  float m6 = fmaxf(vm5, fmaxf(vm6, vm7));
  float m7 = fmaxf(vm6, fmaxf(vm7, vmR));

  pk = 0;
  if (c0.x >= m0) pk |= 1u;
  if (c0.y >= m1) pk |= 2u;
  if (c0.z >= m2) pk |= 4u;
  if (c0.w >= m3) pk |= 8u;
  if (c1.x >= m4) pk |= 16u;
  if (c1.y >= m5) pk |= 32u;
  if (c1.z >= m6) pk |= 64u;
  if (c1.w >= m7) pk |= 128u;
  cv[0]=c0.x; cv[1]=c0.y; cv[2]=c0.z; cv[3]=c0.w;
  cv[4]=c1.x; cv[5]=c1.y; cv[6]=c1.z; cv[7]=c1.w;
}

// ============ Kernel 1: NMS -> per-block segment + per-map 12-bit global hist ============
__global__ __launch_bounds__(512) void k_nms(
    const float* __restrict__ hm, uint64_t* __restrict__ seg_all,
    uint32_t* __restrict__ cnt, uint32_t* __restrict__ ghist)
{
  __shared__ uint32_t lhist[4096];   // 16 KB
  __shared__ uint32_t ctr;
  const int bid = blockIdx.x;
  const int m = bid >> 4, p = bid & (PBANDS - 1);
  const int tid = threadIdx.x, lane = tid & 63, w = tid >> 6;
  const float* map = hm + (size_t)m * HWp;
  uint64_t* dst = seg_all + (size_t)bid * CAPB;
  const int y0 = p * BAND + w * 4;
  const int xb = lane * 8;

  for (int i = tid; i < 4096; i += 512) lhist[i] = 0;
  if (tid == 0) ctr = 0;
  __syncthreads();

  // upfront load of the 6 rows this wave needs (12 independent float4 loads)
  const float4 NEG4 = make_float4(-INFINITY,-INFINITY,-INFINITY,-INFINITY);
  float4 ra[6], rb[6];
  #pragma unroll
  for (int r = 0; r < 6; ++r) {
    const int yy = y0 - 1 + r;
    if (yy >= 0 && yy < Hd) {
      const float* rp = map + (size_t)yy * Wd + xb;
      ra[r] = *(const float4*)rp; rb[r] = *(const float4*)(rp + 4);
    } else { ra[r] = NEG4; rb[r] = NEG4; }
  }

  #pragma unroll
  for (int r = 0; r < 4; ++r) {
    uint32_t pk; float cv[8];
    nms_row(ra[r], rb[r], ra[r+1], rb[r+1], ra[r+2], rb[r+2], lane, pk, cv);
    const uint32_t np = (uint32_t)__popc(pk);
    uint32_t incl = np;
    #pragma unroll
    for (int d = 1; d < 64; d <<= 1) { uint32_t u = __shfl_up(incl, d); if (lane >= d) incl += u; }
    const uint32_t tot = __shfl(incl, 63);
    if (!tot) continue;
    uint32_t b0 = 0;
    if (lane == 0) b0 = atomicAdd(&ctr, tot);
    b0 = __shfl(b0, 0);
    uint32_t pos = b0 + incl - np;
    const uint32_t ib = (uint32_t)((y0 + r) * Wd + xb);
    #pragma unroll
    for (int i = 0; i < 8; ++i) {
      if ((pk >> i) & 1u) {
        const uint32_t fb = flipbits(cv[i]);
        if (pos < (uint32_t)CAPB)
          dst[pos] = ((uint64_t)fb << 32) | (uint32_t)(~(ib + (uint32_t)i));
        atomicAdd(&lhist[fb >> 20], 1u);   // counted even if store drops
        ++pos;
      }
    }
  }
  __syncthreads();
  if (tid == 0) cnt[bid] = (ctr < (uint32_t)CAPB) ? ctr : (uint32_t)CAPB;
  // sparse merge into per-map global hist (~few hundred nonzero bins)
  uint32_t* gh = ghist + (size_t)m * 4096;
  for (int i = tid; i < 4096; i += 512) {
    const uint32_t v = lhist[i];
    if (v) atomicAdd(&gh[i], v);
  }
}

// ---- threshold finder: 4096 bins, 1024 threads (4 bins/thread), 2 barriers ----
// res: [0]=bin, [1]=krem, [2]=M (count of keys in bins >= bin)
__device__ __forceinline__ void findT4096(
    const uint32_t* hist, const uint32_t target, const int tid, const int lane,
    const int wid, uint32_t* wtot, uint32_t* res)
{
  const uint32_t s = hist[4*tid] + hist[4*tid+1] + hist[4*tid+2] + hist[4*tid+3];
  uint32_t v = s;
  #pragma unroll
  for (int d = 1; d < 64; d <<= 1) { uint32_t u = __shfl_down(v, d); if (lane + d < 64) v += u; }
  if (lane == 0) wtot[wid] = v;
  __syncthreads();
  uint32_t above = 0;
  for (int ww = wid + 1; ww < 16; ++ww) above += wtot[ww];
  const uint32_t gsuf = v + above;
  if (gsuf >= target && (gsuf - s) < target) {
    uint32_t cum = gsuf - s;
    for (int b = 4*tid + 3; b >= 4*tid; --b) {
      cum += hist[b];
      if (cum >= target) { res[0]=(uint32_t)b; res[1]=target-(cum-hist[b]); res[2]=cum; break; }
    }
  }
  __syncthreads();
}

__device__ __forceinline__ uint64_t cexch(uint64_t mine, uint64_t part, bool wantMax) {
  uint64_t mx = mine > part ? mine : part;
  uint64_t mn = mine > part ? part : mine;
  return wantMax ? mx : mn;
}

// ---- bitonic sort 1024 keys desc, 1 elem/thread (1024 threads) ----
__device__ void bitonic1024_1t(uint64_t& e0, uint64_t* sbuf, int tid, int lane)
{
  for (int k = 2; k <= 1024; k <<= 1) {
    for (int j = k >> 1; j > 0; j >>= 1) {
      const bool up = ((tid & k) == 0);
      if (j >= 64) {
        __syncthreads();
        sbuf[tid] = e0;
        __syncthreads();
        uint64_t q = sbuf[tid ^ j];
        e0 = cexch(e0, q, up == ((tid & j) == 0));
      } else {
        uint64_t q = __shfl_xor((unsigned long long)e0, j);
        e0 = cexch(e0, q, up == ((lane & j) == 0));
      }
    }
  }
  __syncthreads();
  sbuf[tid] = e0;
  __syncthreads();
}

// ---- bitonic sort 2048 keys desc, 2 elems/thread (1024 threads) — fallback ----
__device__ void bitonic2048_reg(uint64_t& e0, uint64_t& e1, uint64_t* sbuf, int tid, int lane)
{
  const int i1 = tid + 1024;
  for (int k = 2; k <= 2048; k <<= 1) {
    for (int j = k >> 1; j > 0; j >>= 1) {
      if (j >= 1024) {
        uint64_t mx = e0 > e1 ? e0 : e1;
        uint64_t mn = e0 > e1 ? e1 : e0;
        e0 = mx; e1 = mn;
      } else if (j >= 64) {
        __syncthreads();
        sbuf[tid] = e0; sbuf[i1] = e1;
        __syncthreads();
        uint64_t q0 = sbuf[tid ^ j];
        uint64_t q1 = sbuf[i1 ^ j];
        bool amS = ((tid & j) == 0);
        e0 = cexch(e0, q0, ((tid & k) == 0) == amS);
        e1 = cexch(e1, q1, ((i1  & k) == 0) == amS);
      } else {
        uint64_t q0 = __shfl_xor((unsigned long long)e0, j);
        uint64_t q1 = __shfl_xor((unsigned long long)e1, j);
        bool amS = ((lane & j) == 0);
        e0 = cexch(e0, q0, ((tid & k) == 0) == amS);
        e1 = cexch(e1, q1, ((i1  & k) == 0) == amS);
      }
    }
  }
  __syncthreads();
  sbuf[tid] = e0; sbuf[i1] = e1;
  __syncthreads();
}

// ============ Kernel 2: per-map top-500 (hist precomputed) ============
__global__ __launch_bounds__(1024) void k_select(
    const uint64_t* __restrict__ seg_all, const uint32_t* __restrict__ cnt,
    const uint32_t* __restrict__ ghist,
    float* __restrict__ s1_scores, uint32_t* __restrict__ s1_inds)
{
  __shared__ uint32_t hist[4096];   // 16 KB
  __shared__ uint64_t csel[2048];   // 16 KB
  __shared__ uint32_t segn[16];
  __shared__ uint32_t wtot[16];
  __shared__ uint32_t res[4];       // 0:bin 1:krem 2:M0 3:append ctr

  const int m = blockIdx.x;
  const int tid = threadIdx.x, lane = tid & 63, wid = tid >> 6;
  const uint64_t lt = (1ull << lane) - 1ull;

  for (int i = tid; i < 4096; i += 1024) hist[i] = ghist[(size_t)m * 4096 + i];
  if (tid < 16) segn[tid] = min(cnt[m * PBANDS + tid], (uint32_t)CAPB);
  if (tid == 0) res[3] = 0;
  __syncthreads();

  uint32_t n = 0;
  #pragma unroll
  for (int s = 0; s < 16; ++s) n += segn[s];   // broadcast LDS reads

  const uint64_t* sg = seg_all + (size_t)(m * PBANDS + wid) * CAPB;
  const uint32_t sn = segn[wid];

  uint32_t shift = 20, thr = 0;
  if (n > 512) {
    findT4096(hist, KTOP, tid, lane, wid, wtot, res);
    const uint32_t T1 = res[0], krem = res[1], M0 = res[2];
    __syncthreads();
    if (M0 <= 2048u) {
      thr = T1;
    } else {
      // cold path: refine 12 more bits over keys in bin T1
      for (int i = tid; i < 4096; i += 1024) hist[i] = 0;
      __syncthreads();
      for (uint32_t i = (uint32_t)lane; i < sn; i += 64u) {
        const uint32_t f = (uint32_t)(sg[i] >> 32);
        if ((f >> 20) == T1) atomicAdd(&hist[(f >> 8) & 4095u], 1u);
      }
      __syncthreads();
      findT4096(hist, krem, tid, lane, wid, wtot, res);
      shift = 8; thr = (T1 << 12) | res[0];
      __syncthreads();
    }
  }

  // ---- compact survivors into csel (4-wide ILP loads, wave-aggregated append) ----
  for (uint32_t base = 0; base < sn; base += 256u) {
    const uint32_t i0 = base + (uint32_t)lane, i1 = i0 + 64u, i2 = i0 + 128u, i3 = i0 + 192u;
    uint64_t k0 = 0, k1 = 0, k2 = 0, k3 = 0;
    if (i0 < sn) k0 = sg[i0];
    if (i1 < sn) k1 = sg[i1];
    if (i2 < sn) k2 = sg[i2];
    if (i3 < sn) k3 = sg[i3];
    const bool p0 = (i0 < sn) && (((uint32_t)(k0 >> 32) >> shift) >= thr);
    const bool p1 = (i1 < sn) && (((uint32_t)(k1 >> 32) >> shift) >= thr);
    const bool p2 = (i2 < sn) && (((uint32_t)(k2 >> 32) >> shift) >= thr);
    const bool p3 = (i3 < sn) && (((uint32_t)(k3 >> 32) >> shift) >= thr);
    #define APP(K, P) {                                                  \
      const unsigned long long mask = __ballot(P);                       \
      if (mask) {                                                        \
        uint32_t b = 0;                                                  \
        if (lane == 0) b = atomicAdd(&res[3], (uint32_t)__popcll(mask)); \
        b = __shfl(b, 0);                                                \
        if (P) {                                                         \
          const uint32_t pp = b + (uint32_t)__popcll(mask & lt);         \
          if (pp < 2048u) csel[pp] = K;                                  \
        }                                                                \
      }                                                                  \
    }
    APP(k0, p0) APP(k1, p1) APP(k2, p2) APP(k3, p3)
    #undef APP
  }
  __syncthreads();
  uint32_t M = res[3]; if (M > 2048u) M = 2048u;
  for (uint32_t i = M + (uint32_t)tid; i < 2048u; i += 1024u) csel[i] = 0ull;  // 0-pad
  __syncthreads();

  // ---- sort (block-uniform branch) ----
  if (M <= 1024u) {
    uint64_t e0 = csel[tid];
    bitonic1024_1t(e0, csel, tid, lane);
  } else {
    uint64_t e0 = csel[tid], e1 = csel[tid + 1024];
    bitonic2048_reg(e0, e1, csel, tid, lane);
  }

  if (tid < 512) {
    const uint64_t kk = csel[tid];
    float score; uint32_t idx;
    if (kk == 0ull) { score = 0.0f; idx = 0u; }
    else {
      idx = ~(uint32_t)kk;
      const float v = unflipbits((uint32_t)(kk >> 32));
      score = 1.0f / (1.0f + expf(-v));
    }
    s1_scores[m * 512 + tid] = score;
    s1_inds [m * 512 + tid] = idx;
  }
}

// ============ Kernel 3: per-(batch,class) rank + gather + emit (48 blocks) ============
__global__ __launch_bounds__(512) void k_final(
    const float* __restrict__ s1_scores, const uint32_t* __restrict__ s1_inds,
    const float* __restrict__ cen_offset, const float* __restrict__ direction,
    const float* __restrict__ z_coor, const float* __restrict__ dimf,
    float* __restrict__ out)
{
  __shared__ float ssc[Cn][KTOP];
  const int b = blockIdx.x / Cn, c = blockIdx.x % Cn;
  const int tid = threadIdx.x;

  for (int i = tid; i < Cn * KTOP; i += 512) {
    int cc = i / KTOP, r = i - cc * KTOP;
    ssc[cc][r] = s1_scores[(b * Cn + cc) * 512 + r];
  }
  __syncthreads();

  if (tid < KTOP) {
    const int r = tid;
    const int i = c * KTOP + r;
    const uint64_t mykey = ((uint64_t)flipbits(ssc[c][r]) << 32) | (uint32_t)(~(uint32_t)i);
    int rank = r;
    #pragma unroll
    for (int cd = 1; cd < Cn; ++cd) {
      const int cc = (c + cd) % Cn;
      int lo = 0, hi = KTOP;
      while (lo < hi) {
        int mid = (lo + hi) >> 1;
        uint64_t k2 = ((uint64_t)flipbits(ssc[cc][mid]) << 32)
                    | (uint32_t)(~(uint32_t)(cc * KTOP + mid));
        if (k2 > mykey) lo = mid + 1; else hi = mid;
      }
      rank += lo;
    }
    if (rank < KTOP) {
      const float* co = cen_offset + (size_t)b * 2 * HWp;
      const float* di = direction  + (size_t)b * 2 * HWp;
      const float* zc = z_coor     + (size_t)b * HWp;
      const float* dm = dimf       + (size_t)b * 3 * HWp;
      const int bcx = b * Cn + c;
      const uint32_t ind = s1_inds[bcx * 512 + r];
      float o[10];
      o[0] = ssc[c][r];
      o[1] = (float)(ind & (Wd - 1)) + co[ind];
      o[2] = (float)(ind >> 9) + co[HWp + ind];
      o[3] = zc[ind];
      o[4] = dm[ind];
      o[5] = dm[HWp + ind];
      o[6] = dm[2 * HWp + ind];
      o[7] = di[ind];
      o[8] = di[HWp + ind];
      o[9] = (float)c;
      float* op = out + ((size_t)b * KTOP + rank) * 10;
      #pragma unroll
      for (int q = 0; q < 10; ++q) op[q] = o[q];
    }
  }
}

extern "C" void kernel_launch(void* const* d_in, const int* in_sizes, int n_in,
                              void* d_out, int out_size, void* d_ws, size_t ws_size,
                              hipStream_t stream)
{
  const float* hm         = (const float*)d_in[0];
  const float* cen_offset = (const float*)d_in[1];
  const float* direction  = (const float*)d_in[2];
  const float* z_coor     = (const float*)d_in[3];
  const float* dimf       = (const float*)d_in[4];
  float* out = (float*)d_out;

  // ws: ghist[48*4096]u32 (768KB, zeroed per launch) | cnt[768]u32 (pad 4KB)
  //     | s1_sc[48*512]f32 | s1_id[48*512]u32 | seg[768*4096]u64 (25.2MB)
  char* ws = (char*)d_ws;
  uint32_t* ghist = (uint32_t*)ws;
  size_t o0       = (size_t)NMAP * 4096 * 4;
  uint32_t* cnt   = (uint32_t*)(ws + o0);
  float*    s1_sc = (float*)(ws + o0 + 4096);
  uint32_t* s1_id = (uint32_t*)(ws + o0 + 4096 + (size_t)NMAP * 512 * 4);
  size_t fixed    = o0 + 4096 + (size_t)NMAP * 512 * 4 * 2;
  uint64_t* seg   = (uint64_t*)(ws + fixed);

  hipMemsetAsync(ghist, 0, o0, stream);
  k_nms   <<<NMAP * PBANDS, 512, 0, stream>>>(hm, seg, cnt, ghist);
  k_select<<<NMAP,         1024, 0, stream>>>(seg, cnt, ghist, s1_sc, s1_id);
  k_final <<<Bn * Cn,       512, 0, stream>>>(s1_sc, s1_id, cen_offset, direction, z_coor, dimf, out);
}